// Round 1
// baseline (399.296 us; speedup 1.0000x reference)
//
#include <hip/hip_runtime.h>

#define NTM_N 262144
#define NTM_M 128

// ---- workspace layout (float offsets) ----
#define WS_ZETA    0          // 522
#define WS_V       544        // 128
#define WS_KKR     672        // 128  (k_read + 1e-16)
#define WS_KKW     800        // 128  (k_write + 1e-16)
#define WS_ERASE   928        // 128
#define WS_ADD     1056       // 128
#define WS_SCAL    1184       // 32 scalars
#define WS_READACC 1216       // 128
#define WS_PMAXR   1344       // 1024
#define WS_PMAXW   2368       // 1024
#define WS_PSUMR   3392       // 256
#define WS_PSUMW   3648       // 256
#define WS_PWPR    3904       // 256
#define WS_PWPW    4160       // 256
#define WS_SIMR    8192              // N (sim -> exp in place)
#define WS_SIMW    (8192 + NTM_N)    // N
#define WS_WPR     (8192 + 2*NTM_N)  // N
#define WS_WPW     (8192 + 3*NTM_N)  // N
// total ~4.03 MiB of ws

// SCAL: 0 norm_kr, 1 norm_kw, 2 g_r, 3 g_w, 4..6 s_r, 7..9 s_w,
//       10 gamma_r, 11 gamma_w, 12 max_r, 13 max_w, 14 sumexp_r, 15 sumexp_w,
//       16 sumwp_r, 17 sumwp_w

// d_out layout: h_new[1024] | c_new[1024] | mem_new[N*M] | y[128]
#define OUT_H 0
#define OUT_C 1024
#define OUT_MEM 2048
#define OUT_Y (2048 + NTM_N * NTM_M)

__device__ __forceinline__ float sigm_(float x) { return 1.f / (1.f + expf(-x)); }
__device__ __forceinline__ float softplus_(float x) {
  return fmaxf(x, 0.f) + log1pf(expf(-fabsf(x)));
}

// K1: LSTM gates + c_new/h_new.  One wave per hidden unit j (1024 waves).
__global__ __launch_bounds__(256) void lstm_kernel(
    const float* __restrict__ x, const float* __restrict__ h, const float* __restrict__ c,
    const float* __restrict__ W_ih, const float* __restrict__ W_hh,
    const float* __restrict__ b_ih, const float* __restrict__ b_hh,
    float* __restrict__ out) {
  const int wid = (blockIdx.x * blockDim.x + threadIdx.x) >> 6;  // 0..1023
  const int lane = threadIdx.x & 63;
  float s0 = 0.f, s1 = 0.f, s2 = 0.f, s3 = 0.f;
  {
    const float* w0 = W_ih + (size_t)(wid)*128;
    const float* w1 = W_ih + (size_t)(1024 + wid) * 128;
    const float* w2 = W_ih + (size_t)(2048 + wid) * 128;
    const float* w3 = W_ih + (size_t)(3072 + wid) * 128;
    for (int t = lane; t < 128; t += 64) {
      float xv = x[t];
      s0 += xv * w0[t]; s1 += xv * w1[t]; s2 += xv * w2[t]; s3 += xv * w3[t];
    }
  }
  {
    const float* w0 = W_hh + (size_t)(wid)*1024;
    const float* w1 = W_hh + (size_t)(1024 + wid) * 1024;
    const float* w2 = W_hh + (size_t)(2048 + wid) * 1024;
    const float* w3 = W_hh + (size_t)(3072 + wid) * 1024;
    for (int t = lane; t < 1024; t += 64) {
      float hv = h[t];
      s0 += hv * w0[t]; s1 += hv * w1[t]; s2 += hv * w2[t]; s3 += hv * w3[t];
    }
  }
#pragma unroll
  for (int off = 32; off; off >>= 1) {
    s0 += __shfl_xor(s0, off); s1 += __shfl_xor(s1, off);
    s2 += __shfl_xor(s2, off); s3 += __shfl_xor(s3, off);
  }
  if (lane == 0) {
    float ig = s0 + b_ih[wid] + b_hh[wid];
    float fg = s1 + b_ih[1024 + wid] + b_hh[1024 + wid];
    float gg = s2 + b_ih[2048 + wid] + b_hh[2048 + wid];
    float og = s3 + b_ih[3072 + wid] + b_hh[3072 + wid];
    float cn = sigm_(fg) * c[wid] + sigm_(ig) * tanhf(gg);
    out[OUT_C + wid] = cn;
    out[OUT_H + wid] = sigm_(og) * tanhf(cn);
  }
}

// K2: v = c_new @ W_v^T + b_v ; zeta = c_new @ W_zeta^T + b_zeta.  One wave per row.
__global__ __launch_bounds__(256) void zeta_kernel(
    const float* __restrict__ c_new, const float* __restrict__ W_v,
    const float* __restrict__ b_v, const float* __restrict__ W_zeta,
    const float* __restrict__ b_zeta, float* __restrict__ ws) {
  const int wid = (blockIdx.x * blockDim.x + threadIdx.x) >> 6;
  const int lane = threadIdx.x & 63;
  if (wid >= 650) return;
  const float* row;
  float bias;
  int dst;
  if (wid < 522) { row = W_zeta + (size_t)wid * 1024; bias = b_zeta[wid]; dst = WS_ZETA + wid; }
  else { int r = wid - 522; row = W_v + (size_t)r * 1024; bias = b_v[r]; dst = WS_V + r; }
  float p = 0.f;
  for (int t = lane; t < 1024; t += 64) p += c_new[t] * row[t];
#pragma unroll
  for (int off = 32; off; off >>= 1) p += __shfl_xor(p, off);
  if (lane == 0) ws[dst] = p + bias;
}

// K3: derived head parameters + zero read accumulator.  1 block, 128 threads.
__global__ __launch_bounds__(128) void params_kernel(float* __restrict__ ws) {
  const int t = threadIdx.x;
  const float* z = ws + WS_ZETA;
  float kr = z[t] + 1e-16f;
  float kw = z[133 + t] + 1e-16f;
  ws[WS_KKR + t] = kr;
  ws[WS_KKW + t] = kw;
  ws[WS_ERASE + t] = z[266 + t];
  ws[WS_ADD + t] = z[394 + t];
  ws[WS_READACC + t] = 0.f;
  __shared__ float red[128];
  red[t] = kr * kr;
  __syncthreads();
  for (int s = 64; s > 0; s >>= 1) { if (t < s) red[t] += red[t + s]; __syncthreads(); }
  if (t == 0) ws[WS_SCAL + 0] = sqrtf(red[0]);
  __syncthreads();
  red[t] = kw * kw;
  __syncthreads();
  for (int s = 64; s > 0; s >>= 1) { if (t < s) red[t] += red[t + s]; __syncthreads(); }
  if (t == 0) {
    ws[WS_SCAL + 1] = sqrtf(red[0]);
    // read head scalars
    ws[WS_SCAL + 2] = sigm_(z[128]);
    float a0 = z[129], a1 = z[130], a2 = z[131];
    float mx = fmaxf(a0, fmaxf(a1, a2));
    float e0 = expf(a0 - mx), e1 = expf(a1 - mx), e2 = expf(a2 - mx);
    float inv = 1.f / (e0 + e1 + e2);
    ws[WS_SCAL + 4] = e0 * inv; ws[WS_SCAL + 5] = e1 * inv; ws[WS_SCAL + 6] = e2 * inv;
    ws[WS_SCAL + 10] = 1.f + softplus_(z[132]);
    // write head scalars (NOTE: gamma_w from zeta[521] == write_params[-1], per reference)
    ws[WS_SCAL + 3] = sigm_(z[261]);
    float b0 = z[262], b1 = z[263], b2 = z[264];
    float mb = fmaxf(b0, fmaxf(b1, b2));
    float f0 = expf(b0 - mb), f1 = expf(b1 - mb), f2 = expf(b2 - mb);
    float invb = 1.f / (f0 + f1 + f2);
    ws[WS_SCAL + 7] = f0 * invb; ws[WS_SCAL + 8] = f1 * invb; ws[WS_SCAL + 9] = f2 * invb;
    ws[WS_SCAL + 11] = 1.f + softplus_(z[521]);
  }
}

// K4: cosine sims for both heads, one pass over memory. Wave per row (chunked),
// fused per-block max partials.
__global__ __launch_bounds__(256) void sim_kernel(const float* __restrict__ mem,
                                                  float* __restrict__ ws) {
  const int lane = threadIdx.x & 63;
  const int wv = threadIdx.x >> 6;
  const int gw = blockIdx.x * 4 + wv;          // 0..4095
  const int row0 = gw * (NTM_N / 4096);        // 64 rows per wave, contiguous chunk
  const float2 kr = *(const float2*)(ws + WS_KKR + 2 * lane);
  const float2 kw = *(const float2*)(ws + WS_KKW + 2 * lane);
  const float nkr = ws[WS_SCAL + 0];
  const float nkw = ws[WS_SCAL + 1];
  float lmr = -3.0e38f, lmw = -3.0e38f;
  for (int i = row0; i < row0 + NTM_N / 4096; ++i) {
    const float2 m2 = *(const float2*)(mem + (size_t)i * 128 + 2 * lane);
    float m0 = m2.x + 1e-16f, m1 = m2.y + 1e-16f;
    float dr = m0 * kr.x + m1 * kr.y;
    float dw = m0 * kw.x + m1 * kw.y;
    float nn = m0 * m0 + m1 * m1;
#pragma unroll
    for (int off = 32; off; off >>= 1) {
      dr += __shfl_xor(dr, off);
      dw += __shfl_xor(dw, off);
      nn += __shfl_xor(nn, off);
    }
    float nrm = sqrtf(nn);
    float sr = dr / fmaxf(nrm * nkr, 1e-8f);
    float sw = dw / fmaxf(nrm * nkw, 1e-8f);
    if (lane == 0) { ws[WS_SIMR + i] = sr; ws[WS_SIMW + i] = sw; }
    lmr = fmaxf(lmr, sr);
    lmw = fmaxf(lmw, sw);
  }
  __shared__ float smr[4], smw[4];
  if (lane == 0) { smr[wv] = lmr; smw[wv] = lmw; }
  __syncthreads();
  if (threadIdx.x == 0) {
    ws[WS_PMAXR + blockIdx.x] = fmaxf(fmaxf(smr[0], smr[1]), fmaxf(smr[2], smr[3]));
    ws[WS_PMAXW + blockIdx.x] = fmaxf(fmaxf(smw[0], smw[1]), fmaxf(smw[2], smw[3]));
  }
}

// generic dual reduce (1 block)
template <bool IS_MAX>
__global__ __launch_bounds__(256) void reduce2_kernel(float* __restrict__ ws, int srcA, int srcB,
                                                      int n, int dstA, int dstB) {
  const int t = threadIdx.x;
  float a = IS_MAX ? -3.0e38f : 0.f;
  float b = a;
  for (int i = t; i < n; i += 256) {
    float va = ws[srcA + i], vb = ws[srcB + i];
    if (IS_MAX) { a = fmaxf(a, va); b = fmaxf(b, vb); }
    else { a += va; b += vb; }
  }
#pragma unroll
  for (int off = 32; off; off >>= 1) {
    float ax = __shfl_xor(a, off), bx = __shfl_xor(b, off);
    if (IS_MAX) { a = fmaxf(a, ax); b = fmaxf(b, bx); }
    else { a += ax; b += bx; }
  }
  __shared__ float sa[4], sb[4];
  if ((t & 63) == 0) { sa[t >> 6] = a; sb[t >> 6] = b; }
  __syncthreads();
  if (t == 0) {
    float ra = sa[0], rb = sb[0];
    for (int k = 1; k < 4; ++k) {
      if (IS_MAX) { ra = fmaxf(ra, sa[k]); rb = fmaxf(rb, sb[k]); }
      else { ra += sa[k]; rb += sb[k]; }
    }
    ws[dstA] = ra;
    ws[dstB] = rb;
  }
}

// K6: e = exp(sim - max) in place, partial sums per block.
__global__ __launch_bounds__(256) void exp_kernel(float* __restrict__ ws) {
  const int tid = threadIdx.x;
  const int idx = (blockIdx.x * 256 + tid) * 4;
  const float mr = ws[WS_SCAL + 12], mw = ws[WS_SCAL + 13];
  float4 sr = *(float4*)(ws + WS_SIMR + idx);
  float4 sw = *(float4*)(ws + WS_SIMW + idx);
  sr.x = expf(sr.x - mr); sr.y = expf(sr.y - mr);
  sr.z = expf(sr.z - mr); sr.w = expf(sr.w - mr);
  sw.x = expf(sw.x - mw); sw.y = expf(sw.y - mw);
  sw.z = expf(sw.z - mw); sw.w = expf(sw.w - mw);
  *(float4*)(ws + WS_SIMR + idx) = sr;
  *(float4*)(ws + WS_SIMW + idx) = sw;
  float pa = (sr.x + sr.y) + (sr.z + sr.w);
  float pb = (sw.x + sw.y) + (sw.z + sw.w);
#pragma unroll
  for (int off = 32; off; off >>= 1) { pa += __shfl_xor(pa, off); pb += __shfl_xor(pb, off); }
  __shared__ float sa[4], sb[4];
  if ((tid & 63) == 0) { sa[tid >> 6] = pa; sb[tid >> 6] = pb; }
  __syncthreads();
  if (tid == 0) {
    ws[WS_PSUMR + blockIdx.x] = (sa[0] + sa[1]) + (sa[2] + sa[3]);
    ws[WS_PSUMW + blockIdx.x] = (sb[0] + sb[1]) + (sb[2] + sb[3]);
  }
}

// K8: w_g interpolation + shift convolution + gamma power; partial sums of wp.
__global__ __launch_bounds__(256) void convpow_kernel(float* __restrict__ ws,
                                                      const float* __restrict__ rprev,
                                                      const float* __restrict__ wprev) {
  const int tid = threadIdx.x;
  const int base = (blockIdx.x * 256 + tid) * 4;
  const float gr = ws[WS_SCAL + 2], gw_ = ws[WS_SCAL + 3];
  const float s0r = ws[WS_SCAL + 4], s1r = ws[WS_SCAL + 5], s2r = ws[WS_SCAL + 6];
  const float s0w = ws[WS_SCAL + 7], s1w = ws[WS_SCAL + 8], s2w = ws[WS_SCAL + 9];
  const float gar = ws[WS_SCAL + 10], gaw = ws[WS_SCAL + 11];
  const float isr = 1.f / ws[WS_SCAL + 14];
  const float isw = 1.f / ws[WS_SCAL + 15];
  float pa = 0.f, pb = 0.f;
#pragma unroll
  for (int k = 0; k < 4; ++k) {
    int i = base + k;
    int i1 = i + 1; if (i1 >= NTM_N) i1 -= NTM_N;
    int i2 = i + 2; if (i2 >= NTM_N) i2 -= NTM_N;
    // read head
    {
      float f0 = gr * ws[WS_SIMR + i] * isr + (1.f - gr) * rprev[i];
      float f1 = gr * ws[WS_SIMR + i1] * isr + (1.f - gr) * rprev[i1];
      float f2 = gr * ws[WS_SIMR + i2] * isr + (1.f - gr) * rprev[i2];
      float wt = f0 * s0r + f1 * s1r + f2 * s2r;
      float wp = powf(wt, gar);
      ws[WS_WPR + i] = wp;
      pa += wp;
    }
    // write head
    {
      float f0 = gw_ * ws[WS_SIMW + i] * isw + (1.f - gw_) * wprev[i];
      float f1 = gw_ * ws[WS_SIMW + i1] * isw + (1.f - gw_) * wprev[i1];
      float f2 = gw_ * ws[WS_SIMW + i2] * isw + (1.f - gw_) * wprev[i2];
      float wt = f0 * s0w + f1 * s1w + f2 * s2w;
      float wp = powf(wt, gaw);
      ws[WS_WPW + i] = wp;
      pb += wp;
    }
  }
#pragma unroll
  for (int off = 32; off; off >>= 1) { pa += __shfl_xor(pa, off); pb += __shfl_xor(pb, off); }
  __shared__ float sa[4], sb[4];
  if ((tid & 63) == 0) { sa[tid >> 6] = pa; sb[tid >> 6] = pb; }
  __syncthreads();
  if (tid == 0) {
    ws[WS_PWPR + blockIdx.x] = (sa[0] + sa[1]) + (sa[2] + sa[3]);
    ws[WS_PWPW + blockIdx.x] = (sb[0] + sb[1]) + (sb[2] + sb[3]);
  }
}

// K10: mem_new = mem*(1 - ww⊗erase) + ww⊗add ; accumulate read = rw @ mem_new.
__global__ __launch_bounds__(256) void memupdate_kernel(const float* __restrict__ mem,
                                                        float* __restrict__ out_mem,
                                                        float* __restrict__ ws) {
  const int lane = threadIdx.x & 63;
  const int wv = threadIdx.x >> 6;
  const int gw = blockIdx.x * 4 + wv;          // 0..2047
  const int row0 = gw * (NTM_N / 2048);        // 128 rows per wave, contiguous
  const float2 er = *(const float2*)(ws + WS_ERASE + 2 * lane);
  const float2 ad = *(const float2*)(ws + WS_ADD + 2 * lane);
  const float invr = 1.f / (ws[WS_SCAL + 16] + 1e-16f);
  const float invw = 1.f / (ws[WS_SCAL + 17] + 1e-16f);
  float ra = 0.f, rb = 0.f;
  for (int i = row0; i < row0 + NTM_N / 2048; ++i) {
    const float rw = ws[WS_WPR + i] * invr;
    const float wwv = ws[WS_WPW + i] * invw;
    const float2 m2 = *(const float2*)(mem + (size_t)i * 128 + 2 * lane);
    float n0 = m2.x * (1.f - wwv * er.x) + wwv * ad.x;
    float n1 = m2.y * (1.f - wwv * er.y) + wwv * ad.y;
    float2 o2; o2.x = n0; o2.y = n1;
    *(float2*)(out_mem + (size_t)i * 128 + 2 * lane) = o2;
    ra += rw * n0;
    rb += rw * n1;
  }
  __shared__ float sacc[128];
  if (threadIdx.x < 128) sacc[threadIdx.x] = 0.f;
  __syncthreads();
  atomicAdd(&sacc[2 * lane], ra);
  atomicAdd(&sacc[2 * lane + 1], rb);
  __syncthreads();
  if (threadIdx.x < 128) atomicAdd(&ws[WS_READACC + threadIdx.x], sacc[threadIdx.x]);
}

// K11: y = v + read @ W_read^T + b_read, then log_softmax.  1 block, 128 threads.
__global__ __launch_bounds__(128) void final_kernel(const float* __restrict__ W_read,
                                                    const float* __restrict__ b_read,
                                                    float* __restrict__ ws,
                                                    float* __restrict__ out_y) {
  const int t = threadIdx.x;
  __shared__ float rd[128];
  rd[t] = ws[WS_READACC + t];
  __syncthreads();
  float y = ws[WS_V + t] + b_read[t];
  const float* wr = W_read + (size_t)t * 128;
  for (int j = 0; j < 128; ++j) y += rd[j] * wr[j];
  __shared__ float red[128];
  red[t] = y;
  __syncthreads();
  for (int s = 64; s > 0; s >>= 1) { if (t < s) red[t] = fmaxf(red[t], red[t + s]); __syncthreads(); }
  float mx = red[0];
  __syncthreads();
  red[t] = expf(y - mx);
  __syncthreads();
  for (int s = 64; s > 0; s >>= 1) { if (t < s) red[t] += red[t + s]; __syncthreads(); }
  float lse = logf(red[0]);
  out_y[t] = y - mx - lse;
}

extern "C" void kernel_launch(void* const* d_in, const int* in_sizes, int n_in,
                              void* d_out, int out_size, void* d_ws, size_t ws_size,
                              hipStream_t stream) {
  const float* x = (const float*)d_in[0];
  const float* h = (const float*)d_in[1];
  const float* c = (const float*)d_in[2];
  const float* rweights = (const float*)d_in[3];
  const float* wweights = (const float*)d_in[4];
  const float* memory = (const float*)d_in[5];
  const float* W_ih = (const float*)d_in[6];
  const float* W_hh = (const float*)d_in[7];
  const float* b_ih = (const float*)d_in[8];
  const float* b_hh = (const float*)d_in[9];
  const float* W_v = (const float*)d_in[10];
  const float* b_v = (const float*)d_in[11];
  const float* W_zeta = (const float*)d_in[12];
  const float* b_zeta = (const float*)d_in[13];
  const float* W_read = (const float*)d_in[14];
  const float* b_read = (const float*)d_in[15];
  float* out = (float*)d_out;
  float* ws = (float*)d_ws;

  // K1: LSTM (1024 waves)
  lstm_kernel<<<256, 256, 0, stream>>>(x, h, c, W_ih, W_hh, b_ih, b_hh, out);
  // K2: zeta + v GEMV (650 waves), c_new read from d_out
  zeta_kernel<<<163, 256, 0, stream>>>(out + OUT_C, W_v, b_v, W_zeta, b_zeta, ws);
  // K3: head params + zero read accumulator
  params_kernel<<<1, 128, 0, stream>>>(ws);
  // K4: cosine sims (one pass over 128 MiB memory)
  sim_kernel<<<1024, 256, 0, stream>>>(memory, ws);
  // K5: global maxes
  reduce2_kernel<true><<<1, 256, 0, stream>>>(ws, WS_PMAXR, WS_PMAXW, 1024,
                                              WS_SCAL + 12, WS_SCAL + 13);
  // K6: exp + partial sums
  exp_kernel<<<256, 256, 0, stream>>>(ws);
  // K7: softmax denominators
  reduce2_kernel<false><<<1, 256, 0, stream>>>(ws, WS_PSUMR, WS_PSUMW, 256,
                                               WS_SCAL + 14, WS_SCAL + 15);
  // K8: interpolate + shift + pow, partial sums of wp
  convpow_kernel<<<256, 256, 0, stream>>>(ws, rweights, wweights);
  // K9: wp sums
  reduce2_kernel<false><<<1, 256, 0, stream>>>(ws, WS_PWPR, WS_PWPW, 256,
                                               WS_SCAL + 16, WS_SCAL + 17);
  // K10: memory update + read-vector accumulation (second pass over memory)
  memupdate_kernel<<<512, 256, 0, stream>>>(memory, out + OUT_MEM, ws);
  // K11: output head + log_softmax
  final_kernel<<<1, 128, 0, stream>>>(W_read, b_read, ws, out + OUT_Y);
}

// Round 2
// 330.531 us; speedup vs baseline: 1.2080x; 1.2080x over previous
//
#include <hip/hip_runtime.h>

#define NTM_N 262144
#define NTM_M 128

// ---- workspace layout (float offsets) ----
#define WS_ZETA    0          // 522
#define WS_V       544        // 128
#define WS_KKR     672        // 128  (k_read + 1e-16)
#define WS_KKW     800        // 128  (k_write + 1e-16)
#define WS_ERASE   928        // 128
#define WS_ADD     1056       // 128
#define WS_SCAL    1184       // 32 scalars
#define WS_SLAB    1216       // 16*128 = 2048 read-vector accumulator slabs
#define WS_PSUMR   3264       // 2048 (per-block exp sums, read head)
#define WS_PSUMW   5312       // 2048
#define WS_PWPR    7360       // 256
#define WS_PWPW    7616       // 256
#define WS_SIMR    8192              // N : exp(sim_r - 1)
#define WS_SIMW    (8192 + NTM_N)    // N : exp(sim_w - 1)
#define WS_WPR     (8192 + 2*NTM_N)  // N : wp_r
#define WS_WPW     (8192 + 3*NTM_N)  // N : wp_w

// SCAL: 0 norm_kr, 1 norm_kw, 2 g_r, 3 g_w, 4..6 s_r, 7..9 s_w,
//       10 gamma_r, 11 gamma_w, 14 sumexp_r, 15 sumexp_w, 16 sumwp_r, 17 sumwp_w

// d_out layout: h_new[1024] | c_new[1024] | mem_new[N*M] | y[128]
#define OUT_H 0
#define OUT_C 1024
#define OUT_MEM 2048
#define OUT_Y (2048 + NTM_N * NTM_M)

__device__ __forceinline__ float sigm_(float x) { return 1.f / (1.f + expf(-x)); }
__device__ __forceinline__ float softplus_(float x) {
  return fmaxf(x, 0.f) + log1pf(expf(-fabsf(x)));
}

// K1: LSTM. One block per hidden unit j; wave wv computes gate wv's dot product.
__global__ __launch_bounds__(256) void lstm_kernel(
    const float* __restrict__ x, const float* __restrict__ h, const float* __restrict__ c,
    const float* __restrict__ W_ih, const float* __restrict__ W_hh,
    const float* __restrict__ b_ih, const float* __restrict__ b_hh,
    float* __restrict__ out) {
  const int j = blockIdx.x;           // 0..1023
  const int wv = threadIdx.x >> 6;    // gate 0..3 (i,f,g,o)
  const int l = threadIdx.x & 63;
  const int row = wv * 1024 + j;
  float s;
  {
    const float2 xv = *(const float2*)(x + 2 * l);
    const float2 w2 = *(const float2*)(W_ih + (size_t)row * 128 + 2 * l);
    s = xv.x * w2.x + xv.y * w2.y;
  }
  const float* wh = W_hh + (size_t)row * 1024;
#pragma unroll
  for (int it = 0; it < 4; ++it) {
    const int cb = it * 256 + 4 * l;
    const float4 hv = *(const float4*)(h + cb);
    const float4 w4 = *(const float4*)(wh + cb);
    s += hv.x * w4.x + hv.y * w4.y + hv.z * w4.z + hv.w * w4.w;
  }
#pragma unroll
  for (int off = 32; off; off >>= 1) s += __shfl_xor(s, off);
  __shared__ float gate[4];
  if (l == 0) gate[wv] = s + b_ih[row] + b_hh[row];
  __syncthreads();
  if (threadIdx.x == 0) {
    const float cn = sigm_(gate[1]) * c[j] + sigm_(gate[0]) * tanhf(gate[2]);
    out[OUT_C + j] = cn;
    out[OUT_H + j] = sigm_(gate[3]) * tanhf(cn);
  }
}

// K2: zeta / v GEMV. One wave per output row, float4 loads.
__global__ __launch_bounds__(256) void zeta_kernel(
    const float* __restrict__ c_new, const float* __restrict__ W_v,
    const float* __restrict__ b_v, const float* __restrict__ W_zeta,
    const float* __restrict__ b_zeta, float* __restrict__ ws) {
  const int wid = (blockIdx.x * 256 + threadIdx.x) >> 6;
  const int l = threadIdx.x & 63;
  if (wid >= 650) return;
  const float* row;
  float bias;
  int dst;
  if (wid < 522) { row = W_zeta + (size_t)wid * 1024; bias = b_zeta[wid]; dst = WS_ZETA + wid; }
  else { int r = wid - 522; row = W_v + (size_t)r * 1024; bias = b_v[r]; dst = WS_V + r; }
  float s = 0.f;
#pragma unroll
  for (int it = 0; it < 4; ++it) {
    const int cb = it * 256 + 4 * l;
    const float4 cv = *(const float4*)(c_new + cb);
    const float4 w4 = *(const float4*)(row + cb);
    s += cv.x * w4.x + cv.y * w4.y + cv.z * w4.z + cv.w * w4.w;
  }
#pragma unroll
  for (int off = 32; off; off >>= 1) s += __shfl_xor(s, off);
  if (l == 0) ws[dst] = s + bias;
}

// K3: derived head parameters + zero accumulator slabs.  1 block, 128 threads.
__global__ __launch_bounds__(128) void params_kernel(float* __restrict__ ws) {
  const int t = threadIdx.x;
  const float* z = ws + WS_ZETA;
  const float kr = z[t] + 1e-16f;
  const float kw = z[133 + t] + 1e-16f;
  ws[WS_KKR + t] = kr;
  ws[WS_KKW + t] = kw;
  ws[WS_ERASE + t] = z[266 + t];
  ws[WS_ADD + t] = z[394 + t];
#pragma unroll
  for (int sl = 0; sl < 16; ++sl) ws[WS_SLAB + sl * 128 + t] = 0.f;
  __shared__ float red[128];
  red[t] = kr * kr;
  __syncthreads();
  for (int s = 64; s > 0; s >>= 1) { if (t < s) red[t] += red[t + s]; __syncthreads(); }
  if (t == 0) ws[WS_SCAL + 0] = sqrtf(red[0]);
  __syncthreads();
  red[t] = kw * kw;
  __syncthreads();
  for (int s = 64; s > 0; s >>= 1) { if (t < s) red[t] += red[t + s]; __syncthreads(); }
  if (t == 0) {
    ws[WS_SCAL + 1] = sqrtf(red[0]);
    // read head scalars
    ws[WS_SCAL + 2] = sigm_(z[128]);
    float a0 = z[129], a1 = z[130], a2 = z[131];
    float mx = fmaxf(a0, fmaxf(a1, a2));
    float e0 = expf(a0 - mx), e1 = expf(a1 - mx), e2 = expf(a2 - mx);
    float inv = 1.f / (e0 + e1 + e2);
    ws[WS_SCAL + 4] = e0 * inv; ws[WS_SCAL + 5] = e1 * inv; ws[WS_SCAL + 6] = e2 * inv;
    ws[WS_SCAL + 10] = 1.f + softplus_(z[132]);
    // write head scalars (gamma_w from zeta[521] == write_params[-1], per reference)
    ws[WS_SCAL + 3] = sigm_(z[261]);
    float b0 = z[262], b1 = z[263], b2 = z[264];
    float mb = fmaxf(b0, fmaxf(b1, b2));
    float f0 = expf(b0 - mb), f1 = expf(b1 - mb), f2 = expf(b2 - mb);
    float invb = 1.f / (f0 + f1 + f2);
    ws[WS_SCAL + 7] = f0 * invb; ws[WS_SCAL + 8] = f1 * invb; ws[WS_SCAL + 9] = f2 * invb;
    ws[WS_SCAL + 11] = 1.f + softplus_(z[521]);
  }
}

// K4: cosine sims + exp(sim-1) for both heads, one pass.  Wave covers 2 rows per
// iteration (float4/lane); half-wave (32-lane) butterflies.  |sim| <= 1 by
// Cauchy-Schwarz, so exp(sim-1) is a valid stable-softmax numerator (no max pass).
__global__ __launch_bounds__(256) void simexp_kernel(const float* __restrict__ mem,
                                                     float* __restrict__ ws) {
  const int l = threadIdx.x & 63;
  const int wv = threadIdx.x >> 6;
  const int gw = blockIdx.x * 4 + wv;  // 0..8191
  const int half = l >> 5, sl = l & 31;
  const float4 kr = *(const float4*)(ws + WS_KKR + 4 * sl);
  const float4 kw = *(const float4*)(ws + WS_KKW + 4 * sl);
  const float nkr = ws[WS_SCAL + 0];
  const float nkw = ws[WS_SCAL + 1];
  float lsr = 0.f, lsw = 0.f;
  const int row0 = gw * 32;
#pragma unroll 4
  for (int it = 0; it < 16; ++it) {
    const int r = row0 + 2 * it + half;
    const float4 m = *(const float4*)(mem + (size_t)r * 128 + 4 * sl);
    const float m0 = m.x + 1e-16f, m1 = m.y + 1e-16f;
    const float m2 = m.z + 1e-16f, m3 = m.w + 1e-16f;
    float dr = m0 * kr.x + m1 * kr.y + m2 * kr.z + m3 * kr.w;
    float dw = m0 * kw.x + m1 * kw.y + m2 * kw.z + m3 * kw.w;
    float nn = m0 * m0 + m1 * m1 + m2 * m2 + m3 * m3;
#pragma unroll
    for (int off = 16; off; off >>= 1) {
      dr += __shfl_xor(dr, off);
      dw += __shfl_xor(dw, off);
      nn += __shfl_xor(nn, off);
    }
    if (sl == 0) {
      const float nrm = sqrtf(nn);
      const float er = expf(dr / fmaxf(nrm * nkr, 1e-8f) - 1.0f);
      const float ew = expf(dw / fmaxf(nrm * nkw, 1e-8f) - 1.0f);
      ws[WS_SIMR + r] = er;
      ws[WS_SIMW + r] = ew;
      lsr += er;
      lsw += ew;
    }
  }
  __shared__ float sa[8], sb[8];
  if (sl == 0) { sa[wv * 2 + half] = lsr; sb[wv * 2 + half] = lsw; }
  __syncthreads();
  if (threadIdx.x == 0) {
    float ta = 0.f, tb = 0.f;
#pragma unroll
    for (int k = 0; k < 8; ++k) { ta += sa[k]; tb += sb[k]; }
    ws[WS_PSUMR + blockIdx.x] = ta;
    ws[WS_PSUMW + blockIdx.x] = tb;
  }
}

// generic dual sum/max reduce (1 block)
template <bool IS_MAX>
__global__ __launch_bounds__(256) void reduce2_kernel(float* __restrict__ ws, int srcA, int srcB,
                                                      int n, int dstA, int dstB) {
  const int t = threadIdx.x;
  float a = IS_MAX ? -3.0e38f : 0.f;
  float b = a;
  for (int i = t; i < n; i += 256) {
    const float va = ws[srcA + i], vb = ws[srcB + i];
    if (IS_MAX) { a = fmaxf(a, va); b = fmaxf(b, vb); }
    else { a += va; b += vb; }
  }
#pragma unroll
  for (int off = 32; off; off >>= 1) {
    const float ax = __shfl_xor(a, off), bx = __shfl_xor(b, off);
    if (IS_MAX) { a = fmaxf(a, ax); b = fmaxf(b, bx); }
    else { a += ax; b += bx; }
  }
  __shared__ float sa[4], sb[4];
  if ((t & 63) == 0) { sa[t >> 6] = a; sb[t >> 6] = b; }
  __syncthreads();
  if (t == 0) {
    float ra = sa[0], rb = sb[0];
    for (int k = 1; k < 4; ++k) {
      if (IS_MAX) { ra = fmaxf(ra, sa[k]); rb = fmaxf(rb, sb[k]); }
      else { ra += sa[k]; rb += sb[k]; }
    }
    ws[dstA] = ra;
    ws[dstB] = rb;
  }
}

// K6: w_g interpolation + shift conv + gamma power; partial sums of wp.
__global__ __launch_bounds__(256) void convpow_kernel(float* __restrict__ ws,
                                                      const float* __restrict__ rprev,
                                                      const float* __restrict__ wprev) {
  const int tid = threadIdx.x;
  const int base = (blockIdx.x * 256 + tid) * 4;
  const float gr = ws[WS_SCAL + 2], gw_ = ws[WS_SCAL + 3];
  const float s0r = ws[WS_SCAL + 4], s1r = ws[WS_SCAL + 5], s2r = ws[WS_SCAL + 6];
  const float s0w = ws[WS_SCAL + 7], s1w = ws[WS_SCAL + 8], s2w = ws[WS_SCAL + 9];
  const float gar = ws[WS_SCAL + 10], gaw = ws[WS_SCAL + 11];
  const float isr = 1.f / ws[WS_SCAL + 14];
  const float isw = 1.f / ws[WS_SCAL + 15];
  int i4 = base + 4; if (i4 >= NTM_N) i4 -= NTM_N;
  int i5 = base + 5; if (i5 >= NTM_N) i5 -= NTM_N;
  float pa, pb;
  {
    const float4 e0 = *(const float4*)(ws + WS_SIMR + base);
    const float ea = ws[WS_SIMR + i4], eb = ws[WS_SIMR + i5];
    const float4 p0 = *(const float4*)(rprev + base);
    const float pea = rprev[i4], peb = rprev[i5];
    const float wg0 = gr * e0.x * isr + (1.f - gr) * p0.x;
    const float wg1 = gr * e0.y * isr + (1.f - gr) * p0.y;
    const float wg2 = gr * e0.z * isr + (1.f - gr) * p0.z;
    const float wg3 = gr * e0.w * isr + (1.f - gr) * p0.w;
    const float wg4 = gr * ea * isr + (1.f - gr) * pea;
    const float wg5 = gr * eb * isr + (1.f - gr) * peb;
    float4 wp;
    wp.x = powf(wg0 * s0r + wg1 * s1r + wg2 * s2r, gar);
    wp.y = powf(wg1 * s0r + wg2 * s1r + wg3 * s2r, gar);
    wp.z = powf(wg2 * s0r + wg3 * s1r + wg4 * s2r, gar);
    wp.w = powf(wg3 * s0r + wg4 * s1r + wg5 * s2r, gar);
    *(float4*)(ws + WS_WPR + base) = wp;
    pa = (wp.x + wp.y) + (wp.z + wp.w);
  }
  {
    const float4 e0 = *(const float4*)(ws + WS_SIMW + base);
    const float ea = ws[WS_SIMW + i4], eb = ws[WS_SIMW + i5];
    const float4 p0 = *(const float4*)(wprev + base);
    const float pea = wprev[i4], peb = wprev[i5];
    const float wg0 = gw_ * e0.x * isw + (1.f - gw_) * p0.x;
    const float wg1 = gw_ * e0.y * isw + (1.f - gw_) * p0.y;
    const float wg2 = gw_ * e0.z * isw + (1.f - gw_) * p0.z;
    const float wg3 = gw_ * e0.w * isw + (1.f - gw_) * p0.w;
    const float wg4 = gw_ * ea * isw + (1.f - gw_) * pea;
    const float wg5 = gw_ * eb * isw + (1.f - gw_) * peb;
    float4 wp;
    wp.x = powf(wg0 * s0w + wg1 * s1w + wg2 * s2w, gaw);
    wp.y = powf(wg1 * s0w + wg2 * s1w + wg3 * s2w, gaw);
    wp.z = powf(wg2 * s0w + wg3 * s1w + wg4 * s2w, gaw);
    wp.w = powf(wg3 * s0w + wg4 * s1w + wg5 * s2w, gaw);
    *(float4*)(ws + WS_WPW + base) = wp;
    pb = (wp.x + wp.y) + (wp.z + wp.w);
  }
#pragma unroll
  for (int off = 32; off; off >>= 1) { pa += __shfl_xor(pa, off); pb += __shfl_xor(pb, off); }
  __shared__ float sa[4], sb[4];
  if ((tid & 63) == 0) { sa[tid >> 6] = pa; sb[tid >> 6] = pb; }
  __syncthreads();
  if (tid == 0) {
    ws[WS_PWPR + blockIdx.x] = (sa[0] + sa[1]) + (sa[2] + sa[3]);
    ws[WS_PWPW + blockIdx.x] = (sb[0] + sb[1]) + (sb[2] + sb[3]);
  }
}

// K8: mem_new = mem*(1 - ww⊗erase) + ww⊗add ; accumulate read = rw @ mem_new.
// Wave covers 2 rows per iteration (float4/lane); register accumulation, no shuffles.
__global__ __launch_bounds__(256) void memupdate_kernel(const float* __restrict__ mem,
                                                        float* __restrict__ out_mem,
                                                        float* __restrict__ ws) {
  const int l = threadIdx.x & 63;
  const int wv = threadIdx.x >> 6;
  const int gw = blockIdx.x * 4 + wv;  // 0..4095
  const int half = l >> 5, sl = l & 31;
  const float4 er4 = *(const float4*)(ws + WS_ERASE + 4 * sl);
  const float4 ad4 = *(const float4*)(ws + WS_ADD + 4 * sl);
  const float invr = 1.f / (ws[WS_SCAL + 16] + 1e-16f);
  const float invw = 1.f / (ws[WS_SCAL + 17] + 1e-16f);
  float r0 = 0.f, r1 = 0.f, r2 = 0.f, r3 = 0.f;
  const int row0 = gw * 64;
#pragma unroll 4
  for (int it = 0; it < 32; ++it) {
    const int r = row0 + 2 * it + half;
    const float rw = ws[WS_WPR + r] * invr;
    const float wwv = ws[WS_WPW + r] * invw;
    const float4 m = *(const float4*)(mem + (size_t)r * 128 + 4 * sl);
    float4 o;
    o.x = m.x * (1.f - wwv * er4.x) + wwv * ad4.x;
    o.y = m.y * (1.f - wwv * er4.y) + wwv * ad4.y;
    o.z = m.z * (1.f - wwv * er4.z) + wwv * ad4.z;
    o.w = m.w * (1.f - wwv * er4.w) + wwv * ad4.w;
    *(float4*)(out_mem + (size_t)r * 128 + 4 * sl) = o;
    r0 += rw * o.x; r1 += rw * o.y; r2 += rw * o.z; r3 += rw * o.w;
  }
  __shared__ float sacc[128];
  if (threadIdx.x < 128) sacc[threadIdx.x] = 0.f;
  __syncthreads();
  atomicAdd(&sacc[4 * sl + 0], r0);
  atomicAdd(&sacc[4 * sl + 1], r1);
  atomicAdd(&sacc[4 * sl + 2], r2);
  atomicAdd(&sacc[4 * sl + 3], r3);
  __syncthreads();
  if (threadIdx.x < 128)
    atomicAdd(&ws[WS_SLAB + (blockIdx.x & 15) * 128 + threadIdx.x], sacc[threadIdx.x]);
}

// K9: read vector from slabs, y = v + read @ W_read^T + b_read, log_softmax.
__global__ __launch_bounds__(128) void final_kernel(const float* __restrict__ W_read,
                                                    const float* __restrict__ b_read,
                                                    float* __restrict__ ws,
                                                    float* __restrict__ out_y) {
  const int t = threadIdx.x;
  __shared__ float rd[128];
  float acc = 0.f;
#pragma unroll
  for (int s = 0; s < 16; ++s) acc += ws[WS_SLAB + s * 128 + t];
  rd[t] = acc;
  __syncthreads();
  float y = ws[WS_V + t] + b_read[t];
  const float* wr = W_read + (size_t)t * 128;
  for (int j = 0; j < 128; ++j) y += rd[j] * wr[j];
  __shared__ float red[128];
  red[t] = y;
  __syncthreads();
  for (int s = 64; s > 0; s >>= 1) { if (t < s) red[t] = fmaxf(red[t], red[t + s]); __syncthreads(); }
  const float mx = red[0];
  __syncthreads();
  red[t] = expf(y - mx);
  __syncthreads();
  for (int s = 64; s > 0; s >>= 1) { if (t < s) red[t] += red[t + s]; __syncthreads(); }
  const float lse = logf(red[0]);
  out_y[t] = y - mx - lse;
}

extern "C" void kernel_launch(void* const* d_in, const int* in_sizes, int n_in,
                              void* d_out, int out_size, void* d_ws, size_t ws_size,
                              hipStream_t stream) {
  const float* x = (const float*)d_in[0];
  const float* h = (const float*)d_in[1];
  const float* c = (const float*)d_in[2];
  const float* rweights = (const float*)d_in[3];
  const float* wweights = (const float*)d_in[4];
  const float* memory = (const float*)d_in[5];
  const float* W_ih = (const float*)d_in[6];
  const float* W_hh = (const float*)d_in[7];
  const float* b_ih = (const float*)d_in[8];
  const float* b_hh = (const float*)d_in[9];
  const float* W_v = (const float*)d_in[10];
  const float* b_v = (const float*)d_in[11];
  const float* W_zeta = (const float*)d_in[12];
  const float* b_zeta = (const float*)d_in[13];
  const float* W_read = (const float*)d_in[14];
  const float* b_read = (const float*)d_in[15];
  float* out = (float*)d_out;
  float* ws = (float*)d_ws;

  lstm_kernel<<<1024, 256, 0, stream>>>(x, h, c, W_ih, W_hh, b_ih, b_hh, out);
  zeta_kernel<<<163, 256, 0, stream>>>(out + OUT_C, W_v, b_v, W_zeta, b_zeta, ws);
  params_kernel<<<1, 128, 0, stream>>>(ws);
  simexp_kernel<<<2048, 256, 0, stream>>>(memory, ws);
  reduce2_kernel<false><<<1, 256, 0, stream>>>(ws, WS_PSUMR, WS_PSUMW, 2048,
                                               WS_SCAL + 14, WS_SCAL + 15);
  convpow_kernel<<<256, 256, 0, stream>>>(ws, rweights, wweights);
  reduce2_kernel<false><<<1, 256, 0, stream>>>(ws, WS_PWPR, WS_PWPW, 256,
                                               WS_SCAL + 16, WS_SCAL + 17);
  memupdate_kernel<<<1024, 256, 0, stream>>>(memory, out + OUT_MEM, ws);
  final_kernel<<<1, 128, 0, stream>>>(W_read, b_read, ws, out + OUT_Y);
}

// Round 4
// 324.022 us; speedup vs baseline: 1.2323x; 1.0201x over previous
//
#include <hip/hip_runtime.h>

#define NTM_N 262144
#define NTM_M 128

// ---- workspace layout (float offsets) ----
#define WS_ZETA    0          // 522
#define WS_V       544        // 128
#define WS_KKR     672        // 128  (k_read + 1e-16)
#define WS_KKW     800        // 128  (k_write + 1e-16)
#define WS_ERASE   928        // 128
#define WS_ADD     1056       // 128
#define WS_SCAL    1184       // 32 scalars
#define WS_SLAB    1216       // 16*128 = 2048 read-vector accumulator slabs
#define WS_PSUMR   3264       // 2048 per-block exp sums (read head)
#define WS_PSUMW   5312       // 2048
#define WS_PWPR    7360       // 256 per-block wp sums
#define WS_PWPW    7616       // 256
#define WS_SIMR    8192              // N : exp(sim_r - 1)
#define WS_SIMW    (8192 + NTM_N)    // N : exp(sim_w - 1)
#define WS_WPR     (8192 + 2*NTM_N)  // N : wp_r
#define WS_WPW     (8192 + 3*NTM_N)  // N : wp_w

// SCAL: 0 norm_kr, 1 norm_kw, 2 g_r, 3 g_w, 4..6 s_r, 7..9 s_w, 10 gamma_r, 11 gamma_w

// d_out layout: h_new[1024] | c_new[1024] | mem_new[N*M] | y[128]
#define OUT_H 0
#define OUT_C 1024
#define OUT_MEM 2048
#define OUT_Y (2048 + NTM_N * NTM_M)

__device__ __forceinline__ float sigm_(float x) { return 1.f / (1.f + expf(-x)); }
__device__ __forceinline__ float softplus_(float x) {
  return fmaxf(x, 0.f) + log1pf(expf(-fabsf(x)));
}

// Block-wide dual sum; result broadcast to all threads. Contains __syncthreads.
__device__ __forceinline__ void block_sum_pair(float a, float b, float& outa, float& outb) {
#pragma unroll
  for (int off = 32; off; off >>= 1) { a += __shfl_xor(a, off); b += __shfl_xor(b, off); }
  __shared__ float sa_[4], sb_[4];
  const int wv = threadIdx.x >> 6;
  __syncthreads();  // protect reuse across calls
  if ((threadIdx.x & 63) == 0) { sa_[wv] = a; sb_[wv] = b; }
  __syncthreads();
  outa = (sa_[0] + sa_[1]) + (sa_[2] + sa_[3]);
  outb = (sb_[0] + sb_[1]) + (sb_[2] + sb_[3]);
}

// K1: LSTM. One block per hidden unit j; wave wv computes gate wv's dot product.
__global__ __launch_bounds__(256) void lstm_kernel(
    const float* __restrict__ x, const float* __restrict__ h, const float* __restrict__ c,
    const float* __restrict__ W_ih, const float* __restrict__ W_hh,
    const float* __restrict__ b_ih, const float* __restrict__ b_hh,
    float* __restrict__ out) {
  const int j = blockIdx.x;           // 0..1023
  const int wv = threadIdx.x >> 6;    // gate 0..3 (i,f,g,o)
  const int l = threadIdx.x & 63;
  const int row = wv * 1024 + j;
  float s;
  {
    const float2 xv = *(const float2*)(x + 2 * l);
    const float2 w2 = *(const float2*)(W_ih + (size_t)row * 128 + 2 * l);
    s = xv.x * w2.x + xv.y * w2.y;
  }
  const float* wh = W_hh + (size_t)row * 1024;
#pragma unroll
  for (int it = 0; it < 4; ++it) {
    const int cb = it * 256 + 4 * l;
    const float4 hv = *(const float4*)(h + cb);
    const float4 w4 = *(const float4*)(wh + cb);
    s += hv.x * w4.x + hv.y * w4.y + hv.z * w4.z + hv.w * w4.w;
  }
#pragma unroll
  for (int off = 32; off; off >>= 1) s += __shfl_xor(s, off);
  __shared__ float gate[4];
  if (l == 0) gate[wv] = s + b_ih[row] + b_hh[row];
  __syncthreads();
  if (threadIdx.x == 0) {
    const float cn = sigm_(gate[1]) * c[j] + sigm_(gate[0]) * tanhf(gate[2]);
    out[OUT_C + j] = cn;
    out[OUT_H + j] = sigm_(gate[3]) * tanhf(cn);
  }
}

// K2: zeta / v GEMV. One wave per output row, float4 loads.
__global__ __launch_bounds__(256) void zeta_kernel(
    const float* __restrict__ c_new, const float* __restrict__ W_v,
    const float* __restrict__ b_v, const float* __restrict__ W_zeta,
    const float* __restrict__ b_zeta, float* __restrict__ ws) {
  const int wid = (blockIdx.x * 256 + threadIdx.x) >> 6;
  const int l = threadIdx.x & 63;
  if (wid >= 650) return;
  const float* row;
  float bias;
  int dst;
  if (wid < 522) { row = W_zeta + (size_t)wid * 1024; bias = b_zeta[wid]; dst = WS_ZETA + wid; }
  else { int r = wid - 522; row = W_v + (size_t)r * 1024; bias = b_v[r]; dst = WS_V + r; }
  float s = 0.f;
#pragma unroll
  for (int it = 0; it < 4; ++it) {
    const int cb = it * 256 + 4 * l;
    const float4 cv = *(const float4*)(c_new + cb);
    const float4 w4 = *(const float4*)(row + cb);
    s += cv.x * w4.x + cv.y * w4.y + cv.z * w4.z + cv.w * w4.w;
  }
#pragma unroll
  for (int off = 32; off; off >>= 1) s += __shfl_xor(s, off);
  if (l == 0) ws[dst] = s + bias;
}

// K3: derived head parameters + zero accumulator slabs.  1 block, 128 threads.
__global__ __launch_bounds__(128) void params_kernel(float* __restrict__ ws) {
  const int t = threadIdx.x;
  const float* z = ws + WS_ZETA;
  const float kr = z[t] + 1e-16f;
  const float kw = z[133 + t] + 1e-16f;
  ws[WS_KKR + t] = kr;
  ws[WS_KKW + t] = kw;
  ws[WS_ERASE + t] = z[266 + t];
  ws[WS_ADD + t] = z[394 + t];
#pragma unroll
  for (int sl = 0; sl < 16; ++sl) ws[WS_SLAB + sl * 128 + t] = 0.f;
  __shared__ float red[128];
  red[t] = kr * kr;
  __syncthreads();
  for (int s = 64; s > 0; s >>= 1) { if (t < s) red[t] += red[t + s]; __syncthreads(); }
  if (t == 0) ws[WS_SCAL + 0] = sqrtf(red[0]);
  __syncthreads();
  red[t] = kw * kw;
  __syncthreads();
  for (int s = 64; s > 0; s >>= 1) { if (t < s) red[t] += red[t + s]; __syncthreads(); }
  if (t == 0) {
    ws[WS_SCAL + 1] = sqrtf(red[0]);
    // read head scalars
    ws[WS_SCAL + 2] = sigm_(z[128]);
    float a0 = z[129], a1 = z[130], a2 = z[131];
    float mx = fmaxf(a0, fmaxf(a1, a2));
    float e0 = expf(a0 - mx), e1 = expf(a1 - mx), e2 = expf(a2 - mx);
    float inv = 1.f / (e0 + e1 + e2);
    ws[WS_SCAL + 4] = e0 * inv; ws[WS_SCAL + 5] = e1 * inv; ws[WS_SCAL + 6] = e2 * inv;
    ws[WS_SCAL + 10] = 1.f + softplus_(z[132]);
    // write head scalars (gamma_w from zeta[521] == write_params[-1], per reference)
    ws[WS_SCAL + 3] = sigm_(z[261]);
    float b0 = z[262], b1 = z[263], b2 = z[264];
    float mb = fmaxf(b0, fmaxf(b1, b2));
    float f0 = expf(b0 - mb), f1 = expf(b1 - mb), f2 = expf(b2 - mb);
    float invb = 1.f / (f0 + f1 + f2);
    ws[WS_SCAL + 7] = f0 * invb; ws[WS_SCAL + 8] = f1 * invb; ws[WS_SCAL + 9] = f2 * invb;
    ws[WS_SCAL + 11] = 1.f + softplus_(z[521]);
  }
}

// K4: cosine sims + exp(sim-1) for both heads, one pass.  Wave covers 2 rows per
// iteration (float4/lane); half-wave (32-lane) butterflies.  |sim| <= 1 by
// Cauchy-Schwarz, so exp(sim-1) is a valid stable-softmax numerator (no max pass).
__global__ __launch_bounds__(256) void simexp_kernel(const float* __restrict__ mem,
                                                     float* __restrict__ ws) {
  const int l = threadIdx.x & 63;
  const int wv = threadIdx.x >> 6;
  const int gw = blockIdx.x * 4 + wv;  // 0..8191
  const int half = l >> 5, sl = l & 31;
  const float4 kr = *(const float4*)(ws + WS_KKR + 4 * sl);
  const float4 kw = *(const float4*)(ws + WS_KKW + 4 * sl);
  const float nkr = ws[WS_SCAL + 0];
  const float nkw = ws[WS_SCAL + 1];
  float lsr = 0.f, lsw = 0.f;
  const int row0 = gw * 32;
#pragma unroll 4
  for (int it = 0; it < 16; ++it) {
    const int r = row0 + 2 * it + half;
    const float4 m = *(const float4*)(mem + (size_t)r * 128 + 4 * sl);
    const float m0 = m.x + 1e-16f, m1 = m.y + 1e-16f;
    const float m2 = m.z + 1e-16f, m3 = m.w + 1e-16f;
    float dr = m0 * kr.x + m1 * kr.y + m2 * kr.z + m3 * kr.w;
    float dw = m0 * kw.x + m1 * kw.y + m2 * kw.z + m3 * kw.w;
    float nn = m0 * m0 + m1 * m1 + m2 * m2 + m3 * m3;
#pragma unroll
    for (int off = 16; off; off >>= 1) {
      dr += __shfl_xor(dr, off);
      dw += __shfl_xor(dw, off);
      nn += __shfl_xor(nn, off);
    }
    const float nrm = sqrtf(nn);
    const float er = expf(dr / fmaxf(nrm * nkr, 1e-8f) - 1.0f);
    const float ew = expf(dw / fmaxf(nrm * nkw, 1e-8f) - 1.0f);
    if (sl == 0) {
      ws[WS_SIMR + r] = er;
      ws[WS_SIMW + r] = ew;
      lsr += er;
      lsw += ew;
    }
  }
  __shared__ float sa[8], sb[8];
  if (sl == 0) { sa[wv * 2 + half] = lsr; sb[wv * 2 + half] = lsw; }
  __syncthreads();
  if (threadIdx.x == 0) {
    float ta = 0.f, tb = 0.f;
#pragma unroll
    for (int k = 0; k < 8; ++k) { ta += sa[k]; tb += sb[k]; }
    ws[WS_PSUMR + blockIdx.x] = ta;
    ws[WS_PSUMW + blockIdx.x] = tb;
  }
}

// K5: redundant denominator reduce + w_g interpolation + shift conv + gamma power.
// 256 blocks x 256 threads, 4 elems/thread.  Each block re-reduces the 2048
// partial sums itself (16 KB, L2-resident) — no serializing reduce kernel.
__global__ __launch_bounds__(256) void convpow_kernel(float* __restrict__ ws,
                                                      const float* __restrict__ rprev,
                                                      const float* __restrict__ wprev) {
  const int tid = threadIdx.x;
  // --- redundant reduce of exp partial sums (2048 entries each) ---
  float pa = 0.f, pb = 0.f;
#pragma unroll
  for (int k = 0; k < 8; ++k) {
    pa += ws[WS_PSUMR + tid + k * 256];
    pb += ws[WS_PSUMW + tid + k * 256];
  }
  float Sr, Sw;
  block_sum_pair(pa, pb, Sr, Sw);
  const float isr = 1.f / Sr, isw = 1.f / Sw;

  const float gr = ws[WS_SCAL + 2], gw_ = ws[WS_SCAL + 3];
  const float s0r = ws[WS_SCAL + 4], s1r = ws[WS_SCAL + 5], s2r = ws[WS_SCAL + 6];
  const float s0w = ws[WS_SCAL + 7], s1w = ws[WS_SCAL + 8], s2w = ws[WS_SCAL + 9];
  const float gar = ws[WS_SCAL + 10], gaw = ws[WS_SCAL + 11];
  const int base = (blockIdx.x * 256 + tid) * 4;
  const int i4 = (base + 4) & (NTM_N - 1);
  const int i5 = (base + 5) & (NTM_N - 1);
  float suma, sumb;
  {
    const float4 e0 = *(const float4*)(ws + WS_SIMR + base);
    const float ea = ws[WS_SIMR + i4], eb = ws[WS_SIMR + i5];
    const float4 p0 = *(const float4*)(rprev + base);
    const float pea = rprev[i4], peb = rprev[i5];
    const float wg0 = gr * e0.x * isr + (1.f - gr) * p0.x;
    const float wg1 = gr * e0.y * isr + (1.f - gr) * p0.y;
    const float wg2 = gr * e0.z * isr + (1.f - gr) * p0.z;
    const float wg3 = gr * e0.w * isr + (1.f - gr) * p0.w;
    const float wg4 = gr * ea * isr + (1.f - gr) * pea;
    const float wg5 = gr * eb * isr + (1.f - gr) * peb;
    float4 wp;
    wp.x = powf(wg0 * s0r + wg1 * s1r + wg2 * s2r, gar);
    wp.y = powf(wg1 * s0r + wg2 * s1r + wg3 * s2r, gar);
    wp.z = powf(wg2 * s0r + wg3 * s1r + wg4 * s2r, gar);
    wp.w = powf(wg3 * s0r + wg4 * s1r + wg5 * s2r, gar);
    *(float4*)(ws + WS_WPR + base) = wp;
    suma = (wp.x + wp.y) + (wp.z + wp.w);
  }
  {
    const float4 e0 = *(const float4*)(ws + WS_SIMW + base);
    const float ea = ws[WS_SIMW + i4], eb = ws[WS_SIMW + i5];
    const float4 p0 = *(const float4*)(wprev + base);
    const float pea = wprev[i4], peb = wprev[i5];
    const float wg0 = gw_ * e0.x * isw + (1.f - gw_) * p0.x;
    const float wg1 = gw_ * e0.y * isw + (1.f - gw_) * p0.y;
    const float wg2 = gw_ * e0.z * isw + (1.f - gw_) * p0.z;
    const float wg3 = gw_ * e0.w * isw + (1.f - gw_) * p0.w;
    const float wg4 = gw_ * ea * isw + (1.f - gw_) * pea;
    const float wg5 = gw_ * eb * isw + (1.f - gw_) * peb;
    float4 wp;
    wp.x = powf(wg0 * s0w + wg1 * s1w + wg2 * s2w, gaw);
    wp.y = powf(wg1 * s0w + wg2 * s1w + wg3 * s2w, gaw);
    wp.z = powf(wg2 * s0w + wg3 * s1w + wg4 * s2w, gaw);
    wp.w = powf(wg3 * s0w + wg4 * s1w + wg5 * s2w, gaw);
    *(float4*)(ws + WS_WPW + base) = wp;
    sumb = (wp.x + wp.y) + (wp.z + wp.w);
  }
  float Pr, Pw;
  block_sum_pair(suma, sumb, Pr, Pw);
  if (tid == 0) { ws[WS_PWPR + blockIdx.x] = Pr; ws[WS_PWPW + blockIdx.x] = Pw; }
}

// K6: redundant wp-sum reduce + memory update + read accumulation.
// Wave covers 2 rows per iteration (float4/lane); register accumulation.
__global__ __launch_bounds__(256) void memupdate_kernel(const float* __restrict__ mem,
                                                        float* __restrict__ out_mem,
                                                        float* __restrict__ ws) {
  const int tid = threadIdx.x;
  const int l = tid & 63;
  const int wv = tid >> 6;
  const int half = l >> 5, sl = l & 31;
  // --- redundant reduce of wp partial sums (256 entries each) ---
  float Tr, Tw;
  block_sum_pair(ws[WS_PWPR + tid], ws[WS_PWPW + tid], Tr, Tw);
  const float invr = 1.f / (Tr + 1e-16f);
  const float invw = 1.f / (Tw + 1e-16f);

  const int gw = blockIdx.x * 4 + wv;  // 0..4095
  const float4 er4 = *(const float4*)(ws + WS_ERASE + 4 * sl);
  const float4 ad4 = *(const float4*)(ws + WS_ADD + 4 * sl);
  float r0 = 0.f, r1 = 0.f, r2 = 0.f, r3 = 0.f;
  const int row0 = gw * 64;
#pragma unroll 4
  for (int it = 0; it < 32; ++it) {
    const int r = row0 + 2 * it + half;
    const float rw = ws[WS_WPR + r] * invr;
    const float wwv = ws[WS_WPW + r] * invw;
    const float4 m = *(const float4*)(mem + (size_t)r * 128 + 4 * sl);
    float4 o;
    o.x = m.x * (1.f - wwv * er4.x) + wwv * ad4.x;
    o.y = m.y * (1.f - wwv * er4.y) + wwv * ad4.y;
    o.z = m.z * (1.f - wwv * er4.z) + wwv * ad4.z;
    o.w = m.w * (1.f - wwv * er4.w) + wwv * ad4.w;
    *(float4*)(out_mem + (size_t)r * 128 + 4 * sl) = o;
    r0 += rw * o.x; r1 += rw * o.y; r2 += rw * o.z; r3 += rw * o.w;
  }
  __shared__ float sacc[128];
  __syncthreads();
  if (tid < 128) sacc[tid] = 0.f;
  __syncthreads();
  atomicAdd(&sacc[4 * sl + 0], r0);
  atomicAdd(&sacc[4 * sl + 1], r1);
  atomicAdd(&sacc[4 * sl + 2], r2);
  atomicAdd(&sacc[4 * sl + 3], r3);
  __syncthreads();
  if (tid < 128)
    atomicAdd(&ws[WS_SLAB + (blockIdx.x & 15) * 128 + tid], sacc[tid]);
}

// K7: read vector from slabs, y = v + read @ W_read^T + b_read, log_softmax.
__global__ __launch_bounds__(128) void final_kernel(const float* __restrict__ W_read,
                                                    const float* __restrict__ b_read,
                                                    float* __restrict__ ws,
                                                    float* __restrict__ out_y) {
  const int t = threadIdx.x;
  __shared__ float rd[128];
  float acc = 0.f;
#pragma unroll
  for (int s = 0; s < 16; ++s) acc += ws[WS_SLAB + s * 128 + t];
  rd[t] = acc;
  __syncthreads();
  float y = ws[WS_V + t] + b_read[t];
  const float* wr = W_read + (size_t)t * 128;
  for (int j = 0; j < 128; ++j) y += rd[j] * wr[j];
  __shared__ float red[128];
  red[t] = y;
  __syncthreads();
  for (int s = 64; s > 0; s >>= 1) { if (t < s) red[t] = fmaxf(red[t], red[t + s]); __syncthreads(); }
  const float mx = red[0];
  __syncthreads();
  red[t] = expf(y - mx);
  __syncthreads();
  for (int s = 64; s > 0; s >>= 1) { if (t < s) red[t] += red[t + s]; __syncthreads(); }
  const float lse = logf(red[0]);
  out_y[t] = y - mx - lse;
}

extern "C" void kernel_launch(void* const* d_in, const int* in_sizes, int n_in,
                              void* d_out, int out_size, void* d_ws, size_t ws_size,
                              hipStream_t stream) {
  const float* x = (const float*)d_in[0];
  const float* h = (const float*)d_in[1];
  const float* c = (const float*)d_in[2];
  const float* rweights = (const float*)d_in[3];
  const float* wweights = (const float*)d_in[4];
  const float* memory = (const float*)d_in[5];
  const float* W_ih = (const float*)d_in[6];
  const float* W_hh = (const float*)d_in[7];
  const float* b_ih = (const float*)d_in[8];
  const float* b_hh = (const float*)d_in[9];
  const float* W_v = (const float*)d_in[10];
  const float* b_v = (const float*)d_in[11];
  const float* W_zeta = (const float*)d_in[12];
  const float* b_zeta = (const float*)d_in[13];
  const float* W_read = (const float*)d_in[14];
  const float* b_read = (const float*)d_in[15];
  float* out = (float*)d_out;
  float* ws = (float*)d_ws;

  lstm_kernel<<<1024, 256, 0, stream>>>(x, h, c, W_ih, W_hh, b_ih, b_hh, out);
  zeta_kernel<<<163, 256, 0, stream>>>(out + OUT_C, W_v, b_v, W_zeta, b_zeta, ws);
  params_kernel<<<1, 128, 0, stream>>>(ws);
  simexp_kernel<<<2048, 256, 0, stream>>>(memory, ws);
  convpow_kernel<<<256, 256, 0, stream>>>(ws, rweights, wweights);
  memupdate_kernel<<<1024, 256, 0, stream>>>(memory, out + OUT_MEM, ws);
  final_kernel<<<1, 128, 0, stream>>>(W_read, b_read, ws, out + OUT_Y);
}